// Round 4
// baseline (216.974 us; speedup 1.0000x reference)
//
#include <hip/hip_runtime.h>

// TorchGrouper: G=40000, O=64 offsets (4^3 hollow cube), C=64 channels.
// vox: int32 [2,40,400,400]; gpos: f32 [G,4] (b,z,y,x); feat: f32 [100000,64].
// Out concat: sampled_features [1,64,G,64] | gpf [1,3,G,64] | empty_mask [G]
// Wave = one g, lane = o. Feature path via swizzled LDS transpose.
// R3->R4: removed ALL nontemporal hints — theory: nt defeats L2 write-combining,
// draining 256B chunks interleaved across 67 planes -> DRAM row thrash at 3.4 TB/s.

typedef float f32x4 __attribute__((ext_vector_type(4)));

constexpr int G  = 40000;
constexpr int C  = 64;
constexpr int VZ = 40, VY = 400, VX = 400;
constexpr size_t GO = (size_t)G * 64;

__global__ __launch_bounds__(256) void grouper_kernel(
    const int*   __restrict__ vox,
    const float* __restrict__ gpos,
    const float* __restrict__ feat,
    float*       __restrict__ out)
{
    __shared__ __align__(16) float lds[4][64 * 32];   // 32 KB/block

    const int wid  = threadIdx.x >> 6;
    const int lane = threadIdx.x & 63;
    const int g = blockIdx.x * 4 + wid;
    const int o = lane;

    // offsets r = {-3,-2,1,2}
    const int rtab4[4] = {-3, -2, 1, 2};
    const int rx = rtab4[o & 3];          // added to z
    const int ry = rtab4[(o >> 2) & 3];   // added to y
    const int rz = rtab4[(o >> 4) & 3];   // added to x

    const float4 p = ((const float4*)gpos)[g];        // (b,z,y,x)
    const float zf = p.y + (float)rx;
    const float yf = p.z + (float)ry;
    const float xf = p.w + (float)rz;

    const int bi = (int)p.x;                          // trunc-toward-zero
    const int zi = min(max((int)zf, 0), VZ - 1);
    const int yi = min(max((int)yf, 0), VY - 1);
    const int xi = min(max((int)xf, 0), VX - 1);

    const int idx = vox[((bi * VZ + zi) * VY + yi) * VX + xi];

    // ---- gpf [1,3,G,64]: (z,y,x) frac + quirk (+0, +rx, +ry); empty mask
    float* gout = out + C * GO;
    const size_t t = (size_t)g * 64 + o;
    gout[t]          = zf - truncf(zf);
    gout[GO + t]     = yf - truncf(yf) + (float)rx;
    gout[2 * GO + t] = xf - truncf(xf) + (float)ry;
    const int allm1 = __all(idx == -1);
    if (o == 0) gout[3 * GO + g] = allm1 ? 1.0f : 0.0f;

    // ---- sampled_features via LDS transpose
    float* tile = lds[wid];
    const int d  = lane >> 3;   // phase A: row-within-group (0..7)
    const int c4 = lane & 7;    // phase A: col group (0..7)
    const int q  = lane >> 4;   // phase B: col low bits (0..3)
    const int m  = lane & 15;   // phase B: o-group (0..15)

    #pragma unroll
    for (int chunk = 0; chunk < 2; ++chunk) {
        // Phase A: 8 rows per instruction, 16B/lane, swizzled LDS write.
        #pragma unroll
        for (int i = 0; i < 8; ++i) {
            const int r    = i * 8 + d;               // LDS row = offset index o
            const int ridx = __shfl(idx, r);
            const bool emp = ridx < 0;
            const int  rr  = emp ? 0 : ridx;
            f32x4 v = *(const f32x4*)(feat + (size_t)rr * C + chunk * 32 + c4 * 4);
            if (emp) { v.x = 0.0f; v.y = 0.0f; v.z = 0.0f; v.w = 0.0f; }
            const int cs = c4 ^ ((r >> 2) & 7);       // bank swizzle
            *(f32x4*)(tile + r * 32 + cs * 4) = v;
        }
        asm volatile("s_waitcnt lgkmcnt(0)" ::: "memory");

        // Phase B: gather 4 o's per lane from LDS, 1KB dwordx4 store.
        #pragma unroll
        for (int i = 0; i < 8; ++i) {
            const int ip = (i ^ (m & 7)) * 4 + q;     // swizzled col for rows 4m..4m+3
            f32x4 sv;
            sv.x = tile[(m * 4 + 0) * 32 + ip];
            sv.y = tile[(m * 4 + 1) * 32 + ip];
            sv.z = tile[(m * 4 + 2) * 32 + ip];
            sv.w = tile[(m * 4 + 3) * 32 + ip];
            const size_t c = (size_t)(chunk * 32 + i * 4 + q);
            *(f32x4*)(out + c * GO + (size_t)g * 64 + m * 4) = sv;
        }
        asm volatile("s_waitcnt lgkmcnt(0)" ::: "memory");
    }
}

extern "C" void kernel_launch(void* const* d_in, const int* in_sizes, int n_in,
                              void* d_out, int out_size, void* d_ws, size_t ws_size,
                              hipStream_t stream) {
    const int*   vox  = (const int*)d_in[0];
    const float* gpos = (const float*)d_in[1];
    const float* feat = (const float*)d_in[2];
    float*       out  = (float*)d_out;

    const int grid = G / 4;   // 10000 blocks x 256 threads; wave = one g
    grouper_kernel<<<grid, 256, 0, stream>>>(vox, gpos, feat, out);
}

// Round 5
// 200.149 us; speedup vs baseline: 1.0841x; 1.0841x over previous
//
#include <hip/hip_runtime.h>

// TorchGrouper: G=40000, O=64 offsets (4^3 hollow cube), C=64 channels.
// vox: int32 [2,40,400,400]; gpos: f32 [G,4] (b,z,y,x); feat: f32 [100000,64].
// Out concat: sampled_features [1,64,G,64] | gpf [1,3,G,64] | empty_mask [G]
// Wave = one g, lane = o. Feature path via swizzled LDS transpose. nt stores.
// R4->R5: + bijective XCD-aware block swizzle (T1): each XCD owns a contiguous
// g-range so per-plane L2 write-backs become sequential runs per XCD.

typedef float f32x4 __attribute__((ext_vector_type(4)));

constexpr int G  = 40000;
constexpr int C  = 64;
constexpr int VZ = 40, VY = 400, VX = 400;
constexpr size_t GO = (size_t)G * 64;
constexpr int NBLK = G / 4;           // 10000 blocks
constexpr int NXCD = 8;
constexpr int CHUNK = NBLK / NXCD;    // 1250 (exact)

__global__ __launch_bounds__(256) void grouper_kernel(
    const int*   __restrict__ vox,
    const float* __restrict__ gpos,
    const float* __restrict__ feat,
    float*       __restrict__ out)
{
    __shared__ __align__(16) float lds[4][64 * 32];   // 32 KB/block

    // XCD swizzle: hardware XCD = blockIdx.x % 8; give each XCD a contiguous
    // block (and hence g) range. Bijective since NBLK % NXCD == 0.
    const int blk = (blockIdx.x & 7) * CHUNK + (blockIdx.x >> 3);

    const int wid  = threadIdx.x >> 6;
    const int lane = threadIdx.x & 63;
    const int g = blk * 4 + wid;
    const int o = lane;

    // offsets r = {-3,-2,1,2}
    const int rtab4[4] = {-3, -2, 1, 2};
    const int rx = rtab4[o & 3];          // added to z
    const int ry = rtab4[(o >> 2) & 3];   // added to y
    const int rz = rtab4[(o >> 4) & 3];   // added to x

    const float4 p = ((const float4*)gpos)[g];        // (b,z,y,x)
    const float zf = p.y + (float)rx;
    const float yf = p.z + (float)ry;
    const float xf = p.w + (float)rz;

    const int bi = (int)p.x;                          // trunc-toward-zero
    const int zi = min(max((int)zf, 0), VZ - 1);
    const int yi = min(max((int)yf, 0), VY - 1);
    const int xi = min(max((int)xf, 0), VX - 1);

    const int idx = vox[((bi * VZ + zi) * VY + yi) * VX + xi];

    // ---- gpf [1,3,G,64]: (z,y,x) frac + quirk (+0, +rx, +ry); empty mask
    float* gout = out + C * GO;
    const size_t t = (size_t)g * 64 + o;
    __builtin_nontemporal_store(zf - truncf(zf),             gout + t);
    __builtin_nontemporal_store(yf - truncf(yf) + (float)rx, gout + GO + t);
    __builtin_nontemporal_store(xf - truncf(xf) + (float)ry, gout + 2 * GO + t);
    const int allm1 = __all(idx == -1);
    if (o == 0) gout[3 * GO + g] = allm1 ? 1.0f : 0.0f;

    // ---- sampled_features via LDS transpose
    float* tile = lds[wid];
    const int d  = lane >> 3;   // phase A: row-within-group (0..7)
    const int c4 = lane & 7;    // phase A: col group (0..7)
    const int q  = lane >> 4;   // phase B: col low bits (0..3)
    const int m  = lane & 15;   // phase B: o-group (0..15)

    #pragma unroll
    for (int chunk = 0; chunk < 2; ++chunk) {
        // Phase A: 8 rows per instruction, 16B/lane, swizzled LDS write.
        #pragma unroll
        for (int i = 0; i < 8; ++i) {
            const int r    = i * 8 + d;               // LDS row = offset index o
            const int ridx = __shfl(idx, r);
            const bool emp = ridx < 0;
            const int  rr  = emp ? 0 : ridx;
            f32x4 v = *(const f32x4*)(feat + (size_t)rr * C + chunk * 32 + c4 * 4);
            if (emp) { v.x = 0.0f; v.y = 0.0f; v.z = 0.0f; v.w = 0.0f; }
            const int cs = c4 ^ ((r >> 2) & 7);       // bank swizzle
            *(f32x4*)(tile + r * 32 + cs * 4) = v;
        }
        asm volatile("s_waitcnt lgkmcnt(0)" ::: "memory");

        // Phase B: gather 4 o's per lane from LDS, 1KB dwordx4 nt store.
        #pragma unroll
        for (int i = 0; i < 8; ++i) {
            const int ip = (i ^ (m & 7)) * 4 + q;     // swizzled col for rows 4m..4m+3
            f32x4 sv;
            sv.x = tile[(m * 4 + 0) * 32 + ip];
            sv.y = tile[(m * 4 + 1) * 32 + ip];
            sv.z = tile[(m * 4 + 2) * 32 + ip];
            sv.w = tile[(m * 4 + 3) * 32 + ip];
            const size_t c = (size_t)(chunk * 32 + i * 4 + q);
            __builtin_nontemporal_store(sv, (f32x4*)(out + c * GO + (size_t)g * 64 + m * 4));
        }
        asm volatile("s_waitcnt lgkmcnt(0)" ::: "memory");
    }
}

extern "C" void kernel_launch(void* const* d_in, const int* in_sizes, int n_in,
                              void* d_out, int out_size, void* d_ws, size_t ws_size,
                              hipStream_t stream) {
    const int*   vox  = (const int*)d_in[0];
    const float* gpos = (const float*)d_in[1];
    const float* feat = (const float*)d_in[2];
    float*       out  = (float*)d_out;

    grouper_kernel<<<NBLK, 256, 0, stream>>>(vox, gpos, feat, out);
}

// Round 6
// 194.496 us; speedup vs baseline: 1.1156x; 1.0291x over previous
//
#include <hip/hip_runtime.h>

// TorchGrouper: G=40000, O=64 offsets (4^3 hollow cube), C=64 channels.
// vox: int32 [2,40,400,400]; gpos: f32 [G,4] (b,z,y,x); feat: f32 [100000,64].
// Out concat: sampled_features [1,64,G,64] | gpf [1,3,G,64] | empty_mask [G]
// Wave = one g, lane = o. Feature path via swizzled LDS transpose.
// R5->R6: output stores use system-scope non-temporal (sc0 sc1 nt) inline asm.
// Theory: 686MB/replay write stream floods the 256MB Infinity Cache, evicting
// the 25.6MB feature table between row reuses (~25.6x avg reuse). Keeping the
// write stream out of L3 should cut ~600MB of HBM read-miss traffic.

typedef float f32x4 __attribute__((ext_vector_type(4)));

constexpr int G  = 40000;
constexpr int C  = 64;
constexpr int VZ = 40, VY = 400, VX = 400;
constexpr size_t GO = (size_t)G * 64;
constexpr int NBLK = G / 4;           // 10000 blocks
constexpr int NXCD = 8;
constexpr int CHUNK = NBLK / NXCD;    // 1250 (exact)

__device__ __forceinline__ void store_sysnt_x4(float* p, f32x4 v) {
    asm volatile("global_store_dwordx4 %0, %1, off sc0 sc1 nt"
                 :: "v"(p), "v"(v) : "memory");
}
__device__ __forceinline__ void store_sysnt_x1(float* p, float v) {
    asm volatile("global_store_dword %0, %1, off sc0 sc1 nt"
                 :: "v"(p), "v"(v) : "memory");
}

__global__ __launch_bounds__(256) void grouper_kernel(
    const int*   __restrict__ vox,
    const float* __restrict__ gpos,
    const float* __restrict__ feat,
    float*       __restrict__ out)
{
    __shared__ __align__(16) float lds[4][64 * 32];   // 32 KB/block

    // Bijective XCD swizzle (kept from R5; neutral but harmless).
    const int blk = (blockIdx.x & 7) * CHUNK + (blockIdx.x >> 3);

    const int wid  = threadIdx.x >> 6;
    const int lane = threadIdx.x & 63;
    const int g = blk * 4 + wid;
    const int o = lane;

    // offsets r = {-3,-2,1,2}
    const int rtab4[4] = {-3, -2, 1, 2};
    const int rx = rtab4[o & 3];          // added to z
    const int ry = rtab4[(o >> 2) & 3];   // added to y
    const int rz = rtab4[(o >> 4) & 3];   // added to x

    const float4 p = ((const float4*)gpos)[g];        // (b,z,y,x)
    const float zf = p.y + (float)rx;
    const float yf = p.z + (float)ry;
    const float xf = p.w + (float)rz;

    const int bi = (int)p.x;                          // trunc-toward-zero
    const int zi = min(max((int)zf, 0), VZ - 1);
    const int yi = min(max((int)yf, 0), VY - 1);
    const int xi = min(max((int)xf, 0), VX - 1);

    const int idx = vox[((bi * VZ + zi) * VY + yi) * VX + xi];

    // ---- gpf [1,3,G,64]: (z,y,x) frac + quirk (+0, +rx, +ry); empty mask
    float* gout = out + C * GO;
    const size_t t = (size_t)g * 64 + o;
    store_sysnt_x1(gout + t,          zf - truncf(zf));
    store_sysnt_x1(gout + GO + t,     yf - truncf(yf) + (float)rx);
    store_sysnt_x1(gout + 2 * GO + t, xf - truncf(xf) + (float)ry);
    const int allm1 = __all(idx == -1);
    if (o == 0) store_sysnt_x1(gout + 3 * GO + g, allm1 ? 1.0f : 0.0f);

    // ---- sampled_features via LDS transpose
    float* tile = lds[wid];
    const int d  = lane >> 3;   // phase A: row-within-group (0..7)
    const int c4 = lane & 7;    // phase A: col group (0..7)
    const int q  = lane >> 4;   // phase B: col low bits (0..3)
    const int m  = lane & 15;   // phase B: o-group (0..15)

    #pragma unroll
    for (int chunk = 0; chunk < 2; ++chunk) {
        // Phase A: 8 rows per instruction, 16B/lane, swizzled LDS write.
        #pragma unroll
        for (int i = 0; i < 8; ++i) {
            const int r    = i * 8 + d;               // LDS row = offset index o
            const int ridx = __shfl(idx, r);
            const bool emp = ridx < 0;
            const int  rr  = emp ? 0 : ridx;
            f32x4 v = *(const f32x4*)(feat + (size_t)rr * C + chunk * 32 + c4 * 4);
            if (emp) { v.x = 0.0f; v.y = 0.0f; v.z = 0.0f; v.w = 0.0f; }
            const int cs = c4 ^ ((r >> 2) & 7);       // bank swizzle
            *(f32x4*)(tile + r * 32 + cs * 4) = v;
        }
        asm volatile("s_waitcnt lgkmcnt(0)" ::: "memory");

        // Phase B: gather 4 o's per lane from LDS, 1KB dwordx4 store (sys-nt).
        #pragma unroll
        for (int i = 0; i < 8; ++i) {
            const int ip = (i ^ (m & 7)) * 4 + q;     // swizzled col for rows 4m..4m+3
            f32x4 sv;
            sv.x = tile[(m * 4 + 0) * 32 + ip];
            sv.y = tile[(m * 4 + 1) * 32 + ip];
            sv.z = tile[(m * 4 + 2) * 32 + ip];
            sv.w = tile[(m * 4 + 3) * 32 + ip];
            const size_t c = (size_t)(chunk * 32 + i * 4 + q);
            store_sysnt_x4(out + c * GO + (size_t)g * 64 + m * 4, sv);
        }
        asm volatile("s_waitcnt lgkmcnt(0)" ::: "memory");
    }
}

extern "C" void kernel_launch(void* const* d_in, const int* in_sizes, int n_in,
                              void* d_out, int out_size, void* d_ws, size_t ws_size,
                              hipStream_t stream) {
    const int*   vox  = (const int*)d_in[0];
    const float* gpos = (const float*)d_in[1];
    const float* feat = (const float*)d_in[2];
    float*       out  = (float*)d_out;

    grouper_kernel<<<NBLK, 256, 0, stream>>>(vox, gpos, feat, out);
}